// Round 11
// baseline (428.695 us; speedup 1.0000x reference)
//
#include <hip/hip_runtime.h>
#include <hip/hip_bf16.h>
#include <stdint.h>

// Problem constants
#define B_SZ   1024
#define GF     512
#define GC     63
#define NLEAF  64
#define IN_F   512
#define OUT_F  512

typedef float f32x4 __attribute__((ext_vector_type(4)));
typedef __bf16 bf16x8 __attribute__((ext_vector_type(8)));

struct alignas(16) BV8 { __hip_bfloat162 a, b, c, d; };
union PK8 { BV8 v; bf16x8 f; };
union BU { __hip_bfloat162 h; unsigned int u; };

__device__ inline void pack8(const float* f, __hip_bfloat16* dst) {
  BU a, b, c, d;
  a.h = __float22bfloat162_rn(make_float2(f[0], f[1]));
  b.h = __float22bfloat162_rn(make_float2(f[2], f[3]));
  c.h = __float22bfloat162_rn(make_float2(f[4], f[5]));
  d.h = __float22bfloat162_rn(make_float2(f[6], f[7]));
  *(uint4*)dst = make_uint4(a.u, b.u, c.u, d.u);
}

// ---------------------------------------------------------------------------
// Kernel 1: gatings = sigmoid(x_gating @ gw + gb); leaf_probs tree product.
// ---------------------------------------------------------------------------
__global__ __launch_bounds__(512, 2) void k_leafprobs(
    const float* __restrict__ xg, const float* __restrict__ gw,
    const float* __restrict__ gb, float* __restrict__ p_ws)
{
  __shared__ float xsr[GF];
  __shared__ float part[512];
  __shared__ float gates[GC + 1];
  const int b = blockIdx.x;
  const int t = threadIdx.x;

  xsr[t] = xg[(size_t)b * GF + t];
  __syncthreads();

  const int ks = t >> 6, g = t & 63;
  float acc = 0.f;
  if (g < GC) {
    const float* gp = gw + (size_t)(ks * 64) * GC + g;
    const float* xp = &xsr[ks * 64];
#pragma unroll 8
    for (int k = 0; k < 64; ++k) acc += xp[k] * gp[(size_t)k * GC];
  }
  part[t] = acc;
  __syncthreads();

  if (t < GC) {
    float s = gb[t];
#pragma unroll
    for (int r = 0; r < 8; ++r) s += part[r * 64 + t];
    gates[t] = 1.f / (1.f + expf(-s));
  }
  __syncthreads();

  if (t < NLEAF) {
    float v = 1.f;
    int idx = 0, start = 0;
#pragma unroll
    for (int d = 0; d < 6; ++d) {
      int bit = (t >> (5 - d)) & 1;
      float gg = gates[start + idx];
      v *= bit ? (1.f - gg) : gg;
      idx = 2 * idx + bit;
      start += (1 << d);
    }
    p_ws[(size_t)b * NLEAF + t] = v;
  }
}

// ---------------------------------------------------------------------------
// Kernel 2 (FUSED): reads pw fp32 DIRECTLY.
// out[b][o] (+)= sum_{i,l} (x[b,i]*p[b,l]) * pw[o][i][l]
// R11 = R7 structure (BM=256: 4 waves x 64m, BN=64) with a REGISTER DIET to
// reach 3 waves/EU legitimately (R10 forced 4 and spilled to scratch):
//  - rb prefetch 1-deep (-16 VGPR): total ~164 <= 170-budget of (256,3).
//  - xs bf16 (LDS 55->36 KB so LDS allows 3 blocks/CU).
//  - SK=32 -> grid 1024 so 3 blocks/CU can be resident.
// CU-twins (bid, bid+256, ...) share (nt,kc) -> same pw slice, L1/L2-hot.
// ---------------------------------------------------------------------------
#define SK 32
#define KI 16   // 512 / SK

template <bool ATOMIC>
__global__ __launch_bounds__(256, 3) void k_fused(
    const float* __restrict__ x_leaf,   // [1024][512]
    const float* __restrict__ p_ws,     // [1024][64]
    const float* __restrict__ pw,       // [512][512][64]  ([o][i][l])
    float* __restrict__ dst)            // parts [SK][1024][512] or out
{
  __shared__ __hip_bfloat16 xs[256][KI + 2];                 // stride 18: 9.2 KB
  __shared__ __align__(16) __hip_bfloat16 bs[2][64 * 72];    // 18.4 KB

  const int tid  = threadIdx.x;
  const int lane = tid & 63;
  const int wid  = tid >> 6;        // 0..3
  const int quad = lane >> 4;
  const int l15  = lane & 15;

  const int bid = blockIdx.x;       // 1024
  const int nt  = bid & 7;
  const int kc  = (bid >> 3) & 31;  // CU-twins share (nt,kc)
  const int mt  = bid >> 8;         // 0..3

  const int row_m0 = mt * 256;
  const int o0     = nt * 64;
  const int i0     = kc * KI;
  const int wm     = wid * 64;

  // ---- stage x slab [256 rows][KI] as bf16 : one row per thread ----
  {
    const float* src = x_leaf + (size_t)(row_m0 + tid) * IN_F + i0;
#pragma unroll
    for (int q = 0; q < KI / 4; ++q) {
      float4 v = *(const float4*)(src + q * 4);
      BU u0, u1;
      u0.h = __float22bfloat162_rn(make_float2(v.x, v.y));
      u1.h = __float22bfloat162_rn(make_float2(v.z, v.w));
      *(unsigned int*)&xs[tid][q * 4]     = u0.u;
      *(unsigned int*)&xs[tid][q * 4 + 2] = u1.u;
    }
  }

  // ---- p fragments fp32 (reused all K): pr[mi][ks][half4] ----
  f32x4 pr[4][2][2];
#pragma unroll
  for (int mi = 0; mi < 4; ++mi) {
    int row = row_m0 + wm + mi * 16 + l15;
#pragma unroll
    for (int ks = 0; ks < 2; ++ks) {
      const f32x4* src = (const f32x4*)(p_ws + (size_t)row * NLEAF + ks * 32 + quad * 8);
      pr[mi][ks][0] = src[0];
      pr[mi][ks][1] = src[1];
    }
  }
  { // force p-wait out of the K-loop
    float sink = 0.f;
#pragma unroll
    for (int mi = 0; mi < 4; ++mi)
#pragma unroll
      for (int ks = 0; ks < 2; ++ks)
#pragma unroll
        for (int h = 0; h < 2; ++h) {
          f32x4 v = pr[mi][ks][h];
          sink += v.x + v.y + v.z + v.w;
        }
    if (sink == 1.2345678e37f) ((float*)xs)[0] = sink;   // never taken
  }

  // ---- B-load geometry: thread = (br = tid>>2 of 64 o-rows, seg = tid&3) ----
  const int br  = tid >> 2;
  const int seg = tid & 3;
  const float* bsrc0 = pw + ((size_t)(o0 + br) * IN_F + i0) * NLEAF + seg * 16;

  f32x4 acc[4][4];
#pragma unroll
  for (int mi = 0; mi < 4; ++mi)
#pragma unroll
    for (int ni = 0; ni < 4; ++ni)
      acc[mi][ni] = (f32x4)(0.f);

  float4 rb[4];   // 1-deep register prefetch of the fp32 B tile

#define BLOAD(T)                                                              \
  {                                                                           \
    const float4* s_ = (const float4*)(bsrc0 + (size_t)(T) * NLEAF);          \
    rb[0] = s_[0]; rb[1] = s_[1]; rb[2] = s_[2]; rb[3] = s_[3];               \
  }

#define CVT(DBUF)                                                             \
  {                                                                           \
    float f_[16];                                                             \
    *(float4*)&f_[0]  = rb[0];                                                \
    *(float4*)&f_[4]  = rb[1];                                                \
    *(float4*)&f_[8]  = rb[2];                                                \
    *(float4*)&f_[12] = rb[3];                                                \
    __hip_bfloat16* d_ = &bs[DBUF][br * 72 + seg * 16];                       \
    pack8(&f_[0], d_);                                                        \
    pack8(&f_[8], d_ + 8);                                                    \
  }

  BLOAD(0)

#pragma unroll 2
  for (int it = 0; it < KI; ++it) {
    const int buf = it & 1;

    CVT(buf)                           // consume rb (tile it) -> bs[buf]
    if (it + 1 < KI) BLOAD(it + 1)     // refill rb; covered by compute below

    __syncthreads();                   // bs[buf] visible to all waves

    float xv[4];
#pragma unroll
    for (int mi = 0; mi < 4; ++mi)
      xv[mi] = __bfloat162float(xs[wm + mi * 16 + l15][it]);

    const __hip_bfloat16* bsc = &bs[buf][0];
#pragma unroll
    for (int ks = 0; ks < 2; ++ks) {
      bf16x8 af[4];
#pragma unroll
      for (int mi = 0; mi < 4; ++mi) {
        f32x4 lo = pr[mi][ks][0] * xv[mi];
        f32x4 hi = pr[mi][ks][1] * xv[mi];
        PK8 u;
        u.v.a = __float22bfloat162_rn(make_float2(lo.x, lo.y));
        u.v.b = __float22bfloat162_rn(make_float2(lo.z, lo.w));
        u.v.c = __float22bfloat162_rn(make_float2(hi.x, hi.y));
        u.v.d = __float22bfloat162_rn(make_float2(hi.z, hi.w));
        af[mi] = u.f;
      }
#pragma unroll
      for (int ni = 0; ni < 4; ++ni) {
        bf16x8 bfr = *(const bf16x8*)&bsc[(ni * 16 + l15) * 72 + ks * 32 + quad * 8];
#pragma unroll
        for (int mi = 0; mi < 4; ++mi)
          acc[mi][ni] = __builtin_amdgcn_mfma_f32_16x16x32_bf16(
              af[mi], bfr, acc[mi][ni], 0, 0, 0);
      }
    }
  }
#undef BLOAD
#undef CVT

  // ---- epilogue ----
#pragma unroll
  for (int mi = 0; mi < 4; ++mi) {
#pragma unroll
    for (int ni = 0; ni < 4; ++ni) {
      int row = row_m0 + wm + mi * 16 + quad * 4;
      int col = o0 + ni * 16 + l15;
      if (ATOMIC) {
        float* o = dst + (size_t)row * OUT_F + col;
        atomicAdd(o,             acc[mi][ni][0]);
        atomicAdd(o + OUT_F,     acc[mi][ni][1]);
        atomicAdd(o + 2 * OUT_F, acc[mi][ni][2]);
        atomicAdd(o + 3 * OUT_F, acc[mi][ni][3]);
      } else {
        float* o = dst + ((size_t)kc << 19) + (size_t)row * OUT_F + col;
        o[0]         = acc[mi][ni][0];
        o[OUT_F]     = acc[mi][ni][1];
        o[2 * OUT_F] = acc[mi][ni][2];
        o[3 * OUT_F] = acc[mi][ni][3];
      }
    }
  }
}

// ---------------------------------------------------------------------------
// Kernel 3: out[b][o] = sum_kc parts[kc][b][o] + sum_l p[b][l]*pb[o][l]
// ---------------------------------------------------------------------------
__global__ __launch_bounds__(256, 4) void k_reduce(
    const float* __restrict__ parts, const float* __restrict__ p_ws,
    const float* __restrict__ pb, float* __restrict__ out, int nparts)
{
  __shared__ float ps_l[2 * NLEAF];
  const int t  = threadIdx.x;
  const int b0 = blockIdx.x * 2;

  if (t < 32)
    ((f32x4*)ps_l)[t] = ((const f32x4*)(p_ws + (size_t)b0 * NLEAF))[t];
  __syncthreads();

  const int row = b0 + (t >> 7);
  const int c0  = (t & 127) * 4;
  const f32x4* ps = (const f32x4*)&ps_l[(t >> 7) * NLEAF];

  f32x4 a;
#pragma unroll
  for (int jo = 0; jo < 4; ++jo) {
    const f32x4* pbo = (const f32x4*)(pb + (size_t)(c0 + jo) * NLEAF);
    f32x4 s = (f32x4)(0.f);
#pragma unroll
    for (int lv = 0; lv < 16; ++lv) s += pbo[lv] * ps[lv];
    a[jo] = s.x + s.y + s.z + s.w;
  }

#pragma unroll 8
  for (int k = 0; k < nparts; ++k)
    a += *(const f32x4*)(parts + ((size_t)k << 19) + (size_t)row * OUT_F + c0);

  *(f32x4*)(out + (size_t)row * OUT_F + c0) = a;
}

// ---------------------------------------------------------------------------
extern "C" void kernel_launch(void* const* d_in, const int* in_sizes, int n_in,
                              void* d_out, int out_size, void* d_ws, size_t ws_size,
                              hipStream_t stream) {
  const float* xg = (const float*)d_in[0];   // x_gating [1024][512]
  const float* xl = (const float*)d_in[1];   // x_leaf   [1024][512]
  const float* gw = (const float*)d_in[2];   // [512][63]
  const float* gb = (const float*)d_in[3];   // [63]
  const float* pw = (const float*)d_in[4];   // [512][512][64]
  const float* pb = (const float*)d_in[5];   // [512][64]
  float* out = (float*)d_out;

  // ws: p fp32 (256 KB) | parts fp32 [SK][1024][512] (64 MB)
  const size_t P_BYTES = (size_t)B_SZ * NLEAF * 4;
  const size_t SLICE   = (size_t)B_SZ * OUT_F * 4;

  float* p_ws  = (float*)d_ws;
  float* parts = (float*)((char*)d_ws + P_BYTES);

  k_leafprobs<<<dim3(B_SZ), dim3(512), 0, stream>>>(xg, gw, gb, p_ws);

  if (ws_size >= P_BYTES + SK * SLICE) {
    k_fused<false><<<dim3(1024), dim3(256), 0, stream>>>(xl, p_ws, pw, parts);
    k_reduce<<<dim3(512), dim3(256), 0, stream>>>(parts, p_ws, pb, out, SK);
  } else {
    k_reduce<<<dim3(512), dim3(256), 0, stream>>>(parts, p_ws, pb, out, 0);
    k_fused<true><<<dim3(1024), dim3(256), 0, stream>>>(xl, p_ws, pw, out);
  }
}

// Round 12
// 171.527 us; speedup vs baseline: 2.4993x; 2.4993x over previous
//
#include <hip/hip_runtime.h>
#include <hip/hip_bf16.h>
#include <stdint.h>

// Problem constants
#define B_SZ   1024
#define GF     512
#define GC     63
#define NLEAF  64
#define IN_F   512
#define OUT_F  512

typedef float f32x4 __attribute__((ext_vector_type(4)));
typedef __bf16 bf16x8 __attribute__((ext_vector_type(8)));

struct alignas(16) BV8 { __hip_bfloat162 a, b, c, d; };
union PK8 { BV8 v; bf16x8 f; };
union BU { __hip_bfloat162 h; unsigned int u; };

__device__ inline void pack8(const float* f, __hip_bfloat16* dst) {
  BU a, b, c, d;
  a.h = __float22bfloat162_rn(make_float2(f[0], f[1]));
  b.h = __float22bfloat162_rn(make_float2(f[2], f[3]));
  c.h = __float22bfloat162_rn(make_float2(f[4], f[5]));
  d.h = __float22bfloat162_rn(make_float2(f[6], f[7]));
  *(uint4*)dst = make_uint4(a.u, b.u, c.u, d.u);
}

// ---------------------------------------------------------------------------
// Kernel 1: gatings = sigmoid(x_gating @ gw + gb); leaf_probs tree product.
// ---------------------------------------------------------------------------
__global__ __launch_bounds__(512, 2) void k_leafprobs(
    const float* __restrict__ xg, const float* __restrict__ gw,
    const float* __restrict__ gb, float* __restrict__ p_ws)
{
  __shared__ float xsr[GF];
  __shared__ float part[512];
  __shared__ float gates[GC + 1];
  const int b = blockIdx.x;
  const int t = threadIdx.x;

  xsr[t] = xg[(size_t)b * GF + t];
  __syncthreads();

  const int ks = t >> 6, g = t & 63;
  float acc = 0.f;
  if (g < GC) {
    const float* gp = gw + (size_t)(ks * 64) * GC + g;
    const float* xp = &xsr[ks * 64];
#pragma unroll 8
    for (int k = 0; k < 64; ++k) acc += xp[k] * gp[(size_t)k * GC];
  }
  part[t] = acc;
  __syncthreads();

  if (t < GC) {
    float s = gb[t];
#pragma unroll
    for (int r = 0; r < 8; ++r) s += part[r * 64 + t];
    gates[t] = 1.f / (1.f + expf(-s));
  }
  __syncthreads();

  if (t < NLEAF) {
    float v = 1.f;
    int idx = 0, start = 0;
#pragma unroll
    for (int d = 0; d < 6; ++d) {
      int bit = (t >> (5 - d)) & 1;
      float gg = gates[start + idx];
      v *= bit ? (1.f - gg) : gg;
      idx = 2 * idx + bit;
      start += (1 << d);
    }
    p_ws[(size_t)b * NLEAF + t] = v;
  }
}

// ---------------------------------------------------------------------------
// Kernel 2 (FUSED): reads pw fp32 DIRECTLY (no pwb materialization).
// out[b][o] (+)= sum_{i,l} (x[b,i]*p[b,l]) * pw[o][i][l]
// R12 = R7 VERBATIM (best verified: k_fused 54.2 us, no spill, VGPR 116).
// BM=256 (4 waves x 64m), BN=64, KI=32, SK=16, 512 blocks, 2 blocks/CU.
// Per iter: B fp32 tile (64o x 64l = 16 KB) global->VGPR (2-deep reg
// prefetch) -> cvt bf16 -> ds_write (padded rows) -> 1 barrier -> A-build
// in regs (single RN round) + 32 MFMA/wave.
// R8/R10/R11 all proved: pushing past 2 blocks/CU loses more than it gains
// (halved BM doubles FETCH+barriers; forced launch bounds spill to scratch).
// ---------------------------------------------------------------------------
#define SK 16
#define KI 32   // 512 / SK

template <bool ATOMIC>
__global__ __launch_bounds__(256, 2) void k_fused(
    const float* __restrict__ x_leaf,   // [1024][512]
    const float* __restrict__ p_ws,     // [1024][64]
    const float* __restrict__ pw,       // [512][512][64]  ([o][i][l])
    float* __restrict__ dst)            // parts [SK][1024][512] or out
{
  __shared__ __align__(16) float           xs[256][KI + 4];   // 36.9 KB
  __shared__ __align__(16) __hip_bfloat16  bs[2][64 * 72];    // 18.4 KB

  const int tid  = threadIdx.x;
  const int lane = tid & 63;
  const int wid  = tid >> 6;        // 0..3
  const int quad = lane >> 4;
  const int l15  = lane & 15;

  const int bid = blockIdx.x;       // 512
  const int nt  = bid & 7;
  const int mt  = (bid >> 3) & 3;
  const int kc  = bid >> 5;         // 0..15

  const int row_m0 = mt * 256;
  const int o0     = nt * 64;
  const int i0     = kc * KI;
  const int wm     = wid * 64;

  // ---- stage x slab [256 rows][KI] : one row per thread ----
  {
    const float* src = x_leaf + (size_t)(row_m0 + tid) * IN_F + i0;
#pragma unroll
    for (int q = 0; q < KI / 4; ++q)
      *(float4*)&xs[tid][q * 4] = *(const float4*)(src + q * 4);
  }

  // ---- p fragments fp32 (reused all K): pr[mi][ks][half4] ----
  f32x4 pr[4][2][2];
#pragma unroll
  for (int mi = 0; mi < 4; ++mi) {
    int row = row_m0 + wm + mi * 16 + l15;
#pragma unroll
    for (int ks = 0; ks < 2; ++ks) {
      const f32x4* src = (const f32x4*)(p_ws + (size_t)row * NLEAF + ks * 32 + quad * 8);
      pr[mi][ks][0] = src[0];
      pr[mi][ks][1] = src[1];
    }
  }
  { // force p-wait out of the K-loop
    float sink = 0.f;
#pragma unroll
    for (int mi = 0; mi < 4; ++mi)
#pragma unroll
      for (int ks = 0; ks < 2; ++ks)
#pragma unroll
        for (int h = 0; h < 2; ++h) {
          f32x4 v = pr[mi][ks][h];
          sink += v.x + v.y + v.z + v.w;
        }
    if (sink == 1.2345678e37f) xs[0][0] = sink;   // never taken
  }

  // ---- B-load geometry: thread = (br = tid>>2 of 64 o-rows, seg = tid&3) ----
  const int br  = tid >> 2;
  const int seg = tid & 3;
  const float* bsrc0 = pw + ((size_t)(o0 + br) * IN_F + i0) * NLEAF + seg * 16;

  f32x4 acc[4][4];
#pragma unroll
  for (int mi = 0; mi < 4; ++mi)
#pragma unroll
    for (int ni = 0; ni < 4; ++ni)
      acc[mi][ni] = (f32x4)(0.f);

  float4 rb[2][4];   // 2-deep register prefetch of the fp32 B tile

#define BLOAD(T, BUF)                                                         \
  {                                                                           \
    const float4* s_ = (const float4*)(bsrc0 + (size_t)(T) * NLEAF);          \
    rb[BUF][0] = s_[0]; rb[BUF][1] = s_[1];                                   \
    rb[BUF][2] = s_[2]; rb[BUF][3] = s_[3];                                   \
  }

  BLOAD(0, 0)
  BLOAD(1, 1)

#pragma unroll 2
  for (int it = 0; it < KI; ++it) {
    const int buf = it & 1;

    // cvt fp32 tile -> bf16 into LDS (row br, l-range seg*16..+16)
    {
      float f[16];
      *(float4*)&f[0]  = rb[buf][0];
      *(float4*)&f[4]  = rb[buf][1];
      *(float4*)&f[8]  = rb[buf][2];
      *(float4*)&f[12] = rb[buf][3];
      __hip_bfloat16* d = &bs[buf][br * 72 + seg * 16];
      pack8(&f[0], d);
      pack8(&f[8], d + 8);
    }

    if (it + 2 < KI) BLOAD(it + 2, buf)   // refill just-freed regs

    __syncthreads();   // bs[buf] visible to all waves

    float xv[4];
#pragma unroll
    for (int mi = 0; mi < 4; ++mi) xv[mi] = xs[wm + mi * 16 + l15][it];

    const __hip_bfloat16* bsc = &bs[buf][0];
#pragma unroll
    for (int ks = 0; ks < 2; ++ks) {
      bf16x8 af[4];
#pragma unroll
      for (int mi = 0; mi < 4; ++mi) {
        f32x4 lo = pr[mi][ks][0] * xv[mi];
        f32x4 hi = pr[mi][ks][1] * xv[mi];
        PK8 u;
        u.v.a = __float22bfloat162_rn(make_float2(lo.x, lo.y));
        u.v.b = __float22bfloat162_rn(make_float2(lo.z, lo.w));
        u.v.c = __float22bfloat162_rn(make_float2(hi.x, hi.y));
        u.v.d = __float22bfloat162_rn(make_float2(hi.z, hi.w));
        af[mi] = u.f;
      }
#pragma unroll
      for (int ni = 0; ni < 4; ++ni) {
        bf16x8 bfr = *(const bf16x8*)&bsc[(ni * 16 + l15) * 72 + ks * 32 + quad * 8];
#pragma unroll
        for (int mi = 0; mi < 4; ++mi)
          acc[mi][ni] = __builtin_amdgcn_mfma_f32_16x16x32_bf16(
              af[mi], bfr, acc[mi][ni], 0, 0, 0);
      }
    }
  }
#undef BLOAD

  // ---- epilogue ----
#pragma unroll
  for (int mi = 0; mi < 4; ++mi) {
#pragma unroll
    for (int ni = 0; ni < 4; ++ni) {
      int row = row_m0 + wm + mi * 16 + quad * 4;
      int col = o0 + ni * 16 + l15;
      if (ATOMIC) {
        float* o = dst + (size_t)row * OUT_F + col;
        atomicAdd(o,             acc[mi][ni][0]);
        atomicAdd(o + OUT_F,     acc[mi][ni][1]);
        atomicAdd(o + 2 * OUT_F, acc[mi][ni][2]);
        atomicAdd(o + 3 * OUT_F, acc[mi][ni][3]);
      } else {
        float* o = dst + ((size_t)kc << 19) + (size_t)row * OUT_F + col;
        o[0]         = acc[mi][ni][0];
        o[OUT_F]     = acc[mi][ni][1];
        o[2 * OUT_F] = acc[mi][ni][2];
        o[3 * OUT_F] = acc[mi][ni][3];
      }
    }
  }
}

// ---------------------------------------------------------------------------
// Kernel 3: out[b][o] = sum_kc parts[kc][b][o] + sum_l p[b][l]*pb[o][l]
// ---------------------------------------------------------------------------
__global__ __launch_bounds__(256, 4) void k_reduce(
    const float* __restrict__ parts, const float* __restrict__ p_ws,
    const float* __restrict__ pb, float* __restrict__ out, int nparts)
{
  __shared__ float ps_l[2 * NLEAF];
  const int t  = threadIdx.x;
  const int b0 = blockIdx.x * 2;

  if (t < 32)
    ((f32x4*)ps_l)[t] = ((const f32x4*)(p_ws + (size_t)b0 * NLEAF))[t];
  __syncthreads();

  const int row = b0 + (t >> 7);
  const int c0  = (t & 127) * 4;
  const f32x4* ps = (const f32x4*)&ps_l[(t >> 7) * NLEAF];

  f32x4 a;
#pragma unroll
  for (int jo = 0; jo < 4; ++jo) {
    const f32x4* pbo = (const f32x4*)(pb + (size_t)(c0 + jo) * NLEAF);
    f32x4 s = (f32x4)(0.f);
#pragma unroll
    for (int lv = 0; lv < 16; ++lv) s += pbo[lv] * ps[lv];
    a[jo] = s.x + s.y + s.z + s.w;
  }

#pragma unroll 8
  for (int k = 0; k < nparts; ++k)
    a += *(const f32x4*)(parts + ((size_t)k << 19) + (size_t)row * OUT_F + c0);

  *(f32x4*)(out + (size_t)row * OUT_F + c0) = a;
}

// ---------------------------------------------------------------------------
extern "C" void kernel_launch(void* const* d_in, const int* in_sizes, int n_in,
                              void* d_out, int out_size, void* d_ws, size_t ws_size,
                              hipStream_t stream) {
  const float* xg = (const float*)d_in[0];   // x_gating [1024][512]
  const float* xl = (const float*)d_in[1];   // x_leaf   [1024][512]
  const float* gw = (const float*)d_in[2];   // [512][63]
  const float* gb = (const float*)d_in[3];   // [63]
  const float* pw = (const float*)d_in[4];   // [512][512][64]
  const float* pb = (const float*)d_in[5];   // [512][64]
  float* out = (float*)d_out;

  // ws: p fp32 (256 KB) | parts fp32 [SK][1024][512] (32 MB)
  const size_t P_BYTES = (size_t)B_SZ * NLEAF * 4;
  const size_t SLICE   = (size_t)B_SZ * OUT_F * 4;

  float* p_ws  = (float*)d_ws;
  float* parts = (float*)((char*)d_ws + P_BYTES);

  k_leafprobs<<<dim3(B_SZ), dim3(512), 0, stream>>>(xg, gw, gb, p_ws);

  if (ws_size >= P_BYTES + SK * SLICE) {
    k_fused<false><<<dim3(512), dim3(256), 0, stream>>>(xl, p_ws, pw, parts);
    k_reduce<<<dim3(512), dim3(256), 0, stream>>>(parts, p_ws, pb, out, SK);
  } else {
    k_reduce<<<dim3(512), dim3(256), 0, stream>>>(parts, p_ws, pb, out, 0);
    k_fused<true><<<dim3(512), dim3(256), 0, stream>>>(xl, p_ws, pw, out);
  }
}